// Round 1
// baseline (872.500 us; speedup 1.0000x reference)
//
#include <hip/hip_runtime.h>
#include <math.h>

// Fused HQCNN: conv1(1->2,5x5)+relu+pool2 -> conv2(2->16,5x5)+relu+pool2 ->
// fc1(256->64)+relu -> fc2(64->2) -> 2-qubit circuit -> fc3(1->1) -> log_softmax.
// One block = 4 samples, 256 threads, all intermediates in LDS.

#define QSWAP(i_, j_) { float tr=sr[i_]; sr[i_]=sr[j_]; sr[j_]=tr; \
                        float ti=si[i_]; si[i_]=si[j_]; si[j_]=ti; }
// RY on qubit0 (first index): pairs (0,2),(1,3)
#define QRY0(cc, ss) { \
  float a0r=sr[0], a0i=si[0], a1r=sr[2], a1i=si[2]; \
  sr[0]=cc*a0r-ss*a1r; si[0]=cc*a0i-ss*a1i; \
  sr[2]=ss*a0r+cc*a1r; si[2]=ss*a0i+cc*a1i; \
  float b0r=sr[1], b0i=si[1], b1r=sr[3], b1i=si[3]; \
  sr[1]=cc*b0r-ss*b1r; si[1]=cc*b0i-ss*b1i; \
  sr[3]=ss*b0r+cc*b1r; si[3]=ss*b0i+cc*b1i; }
// RY on qubit1 (second index): pairs (0,1),(2,3)
#define QRY1(cc, ss) { \
  float a0r=sr[0], a0i=si[0], a1r=sr[1], a1i=si[1]; \
  sr[0]=cc*a0r-ss*a1r; si[0]=cc*a0i-ss*a1i; \
  sr[1]=ss*a0r+cc*a1r; si[1]=ss*a0i+cc*a1i; \
  float b0r=sr[2], b0i=si[2], b1r=sr[3], b1i=si[3]; \
  sr[2]=cc*b0r-ss*b1r; si[2]=cc*b0i-ss*b1i; \
  sr[3]=ss*b0r+cc*b1r; si[3]=ss*b0i+cc*b1i; }

__global__ __launch_bounds__(256)
void hqcnn_fused(const float* __restrict__ x,    // (B,1,28,28)
                 const float* __restrict__ w1,   // (2,1,5,5)
                 const float* __restrict__ b1,   // (2,)
                 const float* __restrict__ w2,   // (16,2,5,5)
                 const float* __restrict__ b2,   // (16,)
                 const float* __restrict__ fw1,  // (64,256)
                 const float* __restrict__ fb1,  // (64,)
                 const float* __restrict__ fw2,  // (2,64)
                 const float* __restrict__ fb2,  // (2,)
                 const float* __restrict__ fw3,  // (1,1)
                 const float* __restrict__ fb3,  // (1,)
                 const float* __restrict__ qp,   // (8,)
                 float* __restrict__ out)        // (B,2)
{
    __shared__ __align__(16) float xs[4*784];     // 4 samples of 28x28
    __shared__ __align__(16) float p1[4*288];     // [s][c][12][12]
    __shared__ __align__(16) float hbuf[4*256];   // [s][o*16+i*4+j]
    __shared__ __align__(16) float abuf[4*64];    // fc1 outputs
    __shared__ __align__(16) float w1s[52];
    __shared__ float b1s[2];
    __shared__ __align__(16) float w2s[800];
    __shared__ float b2s[16];

    const int t = threadIdx.x;
    const long base = (long)blockIdx.x * 4;

    // ---- stage inputs into LDS ----
    {
        const float4* gx4 = (const float4*)(x + base * 784);
        float4* xs4 = (float4*)xs;
        #pragma unroll
        for (int i = 0; i < 4; ++i) {
            int idx = t + i * 256;
            if (idx < 784) xs4[idx] = gx4[idx];
        }
        if (t < 50) w1s[t] = w1[t];
        if (t < 2)  b1s[t] = b1[t];
        const float4* w24 = (const float4*)w2;
        float4* w2s4 = (float4*)w2s;
        if (t < 200) w2s4[t] = w24[t];
        if (t < 16) b2s[t] = b2[t];
    }
    __syncthreads();

    // ---- conv1 + relu + maxpool2: both channels per patch ----
    // jobs: (s, i, j) : 4*12*12 = 576
    {
        float wreg[50];
        #pragma unroll
        for (int i = 0; i < 50; ++i) wreg[i] = w1s[i];
        float bb[2] = { b1s[0], b1s[1] };
        for (int f = t; f < 576; f += 256) {
            int s = f / 144;
            int r = f - s * 144;
            int i = r / 12;
            int j = r - i * 12;
            const float* xp = xs + s * 784 + (2 * i) * 28 + 2 * j;
            float pat[36];
            #pragma unroll
            for (int u = 0; u < 6; ++u)
                #pragma unroll
                for (int v = 0; v < 6; ++v)
                    pat[u * 6 + v] = xp[u * 28 + v];
            #pragma unroll
            for (int c = 0; c < 2; ++c) {
                float m = -1e30f;
                #pragma unroll
                for (int du = 0; du < 2; ++du)
                    #pragma unroll
                    for (int dv = 0; dv < 2; ++dv) {
                        float acc = bb[c];
                        #pragma unroll
                        for (int u = 0; u < 5; ++u)
                            #pragma unroll
                            for (int v = 0; v < 5; ++v)
                                acc = fmaf(pat[(du + u) * 6 + dv + v],
                                           wreg[c * 25 + u * 5 + v], acc);
                        m = fmaxf(m, acc);
                    }
                p1[s * 288 + c * 144 + i * 12 + j] = fmaxf(m, 0.f);
            }
        }
    }
    __syncthreads();

    // ---- conv2 + relu + maxpool2: two output channels (ob, ob+8) per patch ----
    // jobs f in [0,512): pos=f&15 (i=pos>>2,j=pos&3), ob=(f>>4)&7, s=(f>>7)&3
    {
        for (int f = t; f < 512; f += 256) {
            int pos = f & 15;
            int i = pos >> 2, j = pos & 3;
            int ob = (f >> 4) & 7;
            int s = (f >> 7) & 3;
            float acc[2][4];
            #pragma unroll
            for (int q = 0; q < 4; ++q) { acc[0][q] = b2s[ob]; acc[1][q] = b2s[ob + 8]; }
            #pragma unroll
            for (int c = 0; c < 2; ++c) {
                float pat[36];
                const float* pp = p1 + s * 288 + c * 144 + (2 * i) * 12 + 2 * j;
                #pragma unroll
                for (int u = 0; u < 6; ++u)
                    #pragma unroll
                    for (int v = 0; v < 6; ++v)
                        pat[u * 6 + v] = pp[u * 12 + v];
                #pragma unroll
                for (int oi = 0; oi < 2; ++oi) {
                    const float* wp = w2s + (ob + oi * 8) * 50 + c * 25;
                    #pragma unroll
                    for (int du = 0; du < 2; ++du)
                        #pragma unroll
                        for (int dv = 0; dv < 2; ++dv) {
                            float a = 0.f;
                            #pragma unroll
                            for (int u = 0; u < 5; ++u)
                                #pragma unroll
                                for (int v = 0; v < 5; ++v)
                                    a = fmaf(pat[(du + u) * 6 + dv + v], wp[u * 5 + v], a);
                            acc[oi][du * 2 + dv] += a;
                        }
                }
            }
            #pragma unroll
            for (int oi = 0; oi < 2; ++oi) {
                float m = fmaxf(fmaxf(acc[oi][0], acc[oi][1]),
                                fmaxf(acc[oi][2], acc[oi][3]));
                hbuf[s * 256 + (ob + oi * 8) * 16 + pos] = fmaxf(m, 0.f);
            }
        }
    }
    __syncthreads();

    // ---- fc1 + relu: thread (s = t>>6, k = t&63) ----
    {
        int s = t >> 6, k = t & 63;
        const float4* wrow = (const float4*)(fw1 + k * 256);
        const float4* hv = (const float4*)(hbuf + s * 256);
        float acc = fb1[k];
        #pragma unroll 8
        for (int n = 0; n < 64; ++n) {
            float4 w4 = wrow[n];
            float4 h4 = hv[n];
            acc = fmaf(w4.x, h4.x, acc);
            acc = fmaf(w4.y, h4.y, acc);
            acc = fmaf(w4.z, h4.z, acc);
            acc = fmaf(w4.w, h4.w, acc);
        }
        abuf[s * 64 + k] = fmaxf(acc, 0.f);
    }
    __syncthreads();

    // ---- fc2 + quantum circuit + fc3 + log_softmax: 4 tail threads ----
    if (t < 4) {
        int s = t;
        const float* av = abuf + s * 64;
        float z0 = fb2[0], z1 = fb2[1];
        for (int k = 0; k < 64; ++k) {
            float a = av[k];
            z0 = fmaf(a, fw2[k], z0);
            z1 = fmaf(a, fw2[64 + k], z1);
        }
        float x0 = z0, x1 = z1;
        // init: s[a][b] = 0.5 * exp(i*((a?+1:-1)x0 + (b?+1:-1)x1)), idx = a*2+b
        float sr[4], si[4];
        float th[4] = { -x0 - x1, -x0 + x1, x0 - x1, x0 + x1 };
        #pragma unroll
        for (int q = 0; q < 4; ++q) {
            float sn, cs;
            sincosf(th[q], &sn, &cs);
            sr[q] = 0.5f * cs;
            si[q] = 0.5f * sn;
        }
        // cnot01: new[1][b] = old[1][1-b]  -> swap s10<->s11 (idx 2,3)
        QSWAP(2, 3);
        // phase on qubit1 with ang
        {
            float ang = ((float)M_PI - x0) * ((float)M_PI - x1);
            float sa, ca;
            sincosf(ang, &sa, &ca);
            // b=0 (idx 0,2): * e^{-i ang};  b=1 (idx 1,3): * e^{+i ang}
            float r, im;
            r = sr[0]; im = si[0]; sr[0] = r * ca + im * sa; si[0] = im * ca - r * sa;
            r = sr[2]; im = si[2]; sr[2] = r * ca + im * sa; si[2] = im * ca - r * sa;
            r = sr[1]; im = si[1]; sr[1] = r * ca - im * sa; si[1] = im * ca + r * sa;
            r = sr[3]; im = si[3]; sr[3] = r * ca - im * sa; si[3] = im * ca + r * sa;
        }
        QSWAP(2, 3);
        float cp[8], sp[8];
        #pragma unroll
        for (int g = 0; g < 8; ++g) sincosf(qp[g], &sp[g], &cp[g]);
        QRY0(cp[0], sp[0]);
        QRY1(cp[1], sp[1]);
        QSWAP(2, 3);                 // cnot01
        QRY0(cp[2], sp[2]);
        QRY1(cp[3], sp[3]);
        QSWAP(1, 3);                 // cnot10: swap s01<->s11
        QRY0(cp[4], sp[4]);
        QRY1(cp[5], sp[5]);
        QSWAP(2, 3);                 // cnot01
        QRY0(cp[6], sp[6]);
        QRY1(cp[7], sp[7]);
        // q = p00 - p01 - p10 + p11
        float qv = (sr[0]*sr[0] + si[0]*si[0])
                 - (sr[1]*sr[1] + si[1]*si[1])
                 - (sr[2]*sr[2] + si[2]*si[2])
                 + (sr[3]*sr[3] + si[3]*si[3]);
        float y = fmaf(qv, fw3[0], fb3[0]);
        float l0 = y, l1 = 1.0f - y;
        float m = fmaxf(l0, l1);
        float lse = m + logf(expf(l0 - m) + expf(l1 - m));
        long o = (base + s) * 2;
        out[o + 0] = l0 - lse;
        out[o + 1] = l1 - lse;
    }
}

extern "C" void kernel_launch(void* const* d_in, const int* in_sizes, int n_in,
                              void* d_out, int out_size, void* d_ws, size_t ws_size,
                              hipStream_t stream) {
    const float* x   = (const float*)d_in[0];
    const float* w1  = (const float*)d_in[1];
    const float* b1  = (const float*)d_in[2];
    const float* w2  = (const float*)d_in[3];
    const float* b2  = (const float*)d_in[4];
    const float* fw1 = (const float*)d_in[5];
    const float* fb1 = (const float*)d_in[6];
    const float* fw2 = (const float*)d_in[7];
    const float* fb2 = (const float*)d_in[8];
    const float* fw3 = (const float*)d_in[9];
    const float* fb3 = (const float*)d_in[10];
    const float* qp  = (const float*)d_in[11];
    float* outp = (float*)d_out;

    int B = in_sizes[0] / 784;     // 65536
    int nblk = B / 4;              // 4 samples per block
    hipLaunchKernelGGL(hqcnn_fused, dim3(nblk), dim3(256), 0, stream,
                       x, w1, b1, w2, b2, fw1, fb1, fw2, fb2, fw3, fb3, qp, outp);
}

// Round 2
// 473.338 us; speedup vs baseline: 1.8433x; 1.8433x over previous
//
#include <hip/hip_runtime.h>
#include <math.h>

// Fused HQCNN, round 2.
// Block = 4 samples, 256 threads, wave w <-> sample w for fc1-final/fc2/tail.
// conv1: jobs (s,i,jh) 288x, 2 pooled cols each, register-streamed rows (b128).
// conv2: jobs (s,oc,quad) 256x, 2x2 pooled block each, weights in regs.
// fc1: weight-shared partials (fw1 read once per block) + LDS reduce.
// fc2+quantum+fc3+logsoftmax: per-wave shuffle reduce + redundant tail, fast math.

__global__ __launch_bounds__(256, 4)
void hqcnn_fused(const float* __restrict__ x,    // (B,1,28,28)
                 const float* __restrict__ w1,   // (2,1,5,5)
                 const float* __restrict__ b1,   // (2,)
                 const float* __restrict__ w2,   // (16,2,5,5)
                 const float* __restrict__ b2,   // (16,)
                 const float* __restrict__ fw1,  // (64,256)
                 const float* __restrict__ fb1,  // (64,)
                 const float* __restrict__ fw2,  // (2,64)
                 const float* __restrict__ fb2,  // (2,)
                 const float* __restrict__ fw3,  // (1,1)
                 const float* __restrict__ fb3,  // (1,)
                 const float* __restrict__ qp,   // (8,)
                 float* __restrict__ out)        // (B,2)
{
    __shared__ __align__(16) float xs[4*784];     // 12544 B
    __shared__ __align__(16) float p1[4*288];     // [s][c][12][12], 4608 B
    __shared__ __align__(16) float hbuf[4*256];   // [s][oc*16+pos], 4096 B
    __shared__ __align__(16) float pbuf[4*256];   // fc1 partials [chunk][s][k]
    __shared__ __align__(16) float w2s[16*56];    // padded: [oc][c][28]
    __shared__ float b2s[16];

    const int t = threadIdx.x;
    const long base = (long)blockIdx.x * 4;

    const float4* xs4 = (const float4*)xs;
    const float4* p14 = (const float4*)p1;
    const float4* hb4 = (const float4*)hbuf;
    const float4* w2s4 = (const float4*)w2s;

    // ---- stage x and conv2 weights into LDS ----
    {
        const float4* gx4 = (const float4*)(x + base * 784);
        float4* xw = (float4*)xs;
        #pragma unroll
        for (int i = 0; i < 4; ++i) {
            int idx = t + i * 256;
            if (idx < 784) xw[idx] = gx4[idx];
        }
        for (int idx = t; idx < 800; idx += 256) {
            int oc = idx / 50;
            int rem = idx - oc * 50;
            int c = rem / 25;
            int kk = rem - c * 25;
            w2s[oc * 56 + c * 28 + kk] = w2[idx];
        }
        if (t < 16) b2s[t] = b2[t];
    }
    __syncthreads();

    // ---- conv1 + relu + pool: 288 jobs, each = pooled row i, cols 2jh,2jh+1 ----
    {
        // uniform weights -> scalar loads
        float w1c[50];
        #pragma unroll
        for (int i = 0; i < 50; ++i) w1c[i] = w1[i];
        float bb0 = b1[0], bb1 = b1[1];

        for (int f = t; f < 288; f += 256) {
            int s = f / 72;
            int r = f - s * 72;
            int i = r / 6;
            int jh = r - i * 6;
            float acc[16];   // [c][a][b]
            #pragma unroll
            for (int q = 0; q < 16; ++q) acc[q] = 0.f;
            int rowbase = s * 196 + (2 * i) * 7 + jh;   // float4 index
            #pragma unroll
            for (int u = 0; u < 6; ++u) {
                float4 r0 = xs4[rowbase + u * 7];
                float4 r1 = xs4[rowbase + u * 7 + 1];
                float rr[8] = { r0.x, r0.y, r0.z, r0.w, r1.x, r1.y, r1.z, r1.w };
                #pragma unroll
                for (int a = 0; a < 2; ++a) {
                    if (a <= u && (u - a) <= 4) {
                        const int wu = u - a;
                        #pragma unroll
                        for (int c = 0; c < 2; ++c)
                            #pragma unroll
                            for (int b = 0; b < 4; ++b) {
                                float s0 = acc[c * 8 + a * 4 + b];
                                #pragma unroll
                                for (int v = 0; v < 5; ++v)
                                    s0 = fmaf(rr[b + v], w1c[c * 25 + wu * 5 + v], s0);
                                acc[c * 8 + a * 4 + b] = s0;
                            }
                    }
                }
            }
            // pool 2x2 over (a, b-pairs), +bias, relu
            #pragma unroll
            for (int c = 0; c < 2; ++c) {
                float bias = c ? bb1 : bb0;
                #pragma unroll
                for (int bb = 0; bb < 2; ++bb) {
                    float m = fmaxf(fmaxf(acc[c*8 + 0*4 + 2*bb], acc[c*8 + 0*4 + 2*bb + 1]),
                                    fmaxf(acc[c*8 + 1*4 + 2*bb], acc[c*8 + 1*4 + 2*bb + 1]));
                    p1[s * 288 + c * 144 + i * 12 + 2 * jh + bb] = fmaxf(m + bias, 0.f);
                }
            }
        }
    }
    __syncthreads();

    // ---- conv2 + relu + pool: 256 jobs (s=t>>6, oc=(t>>2)&15, quad=t&3) ----
    {
        int s = t >> 6;
        int oc = (t >> 2) & 15;
        int qi = (t >> 1) & 1;
        int qj = t & 1;
        float acc[16];   // conv block rows 4qi.., cols 4qj.. [a][b]
        #pragma unroll
        for (int q = 0; q < 16; ++q) acc[q] = 0.f;
        #pragma unroll
        for (int c = 0; c < 2; ++c) {
            // weights for (oc, c): 25 floats via 7 float4 reads
            float wv[28];
            {
                const float4* wp = w2s4 + oc * 14 + c * 7;
                #pragma unroll
                for (int j = 0; j < 7; ++j) {
                    float4 w4 = wp[j];
                    wv[j * 4 + 0] = w4.x; wv[j * 4 + 1] = w4.y;
                    wv[j * 4 + 2] = w4.z; wv[j * 4 + 3] = w4.w;
                }
            }
            int rowbase = s * 72 + c * 36 + (4 * qi) * 3 + qj;  // float4 idx
            #pragma unroll
            for (int u = 0; u < 8; ++u) {
                float4 r0 = p14[rowbase + u * 3];
                float4 r1 = p14[rowbase + u * 3 + 1];
                float rr[8] = { r0.x, r0.y, r0.z, r0.w, r1.x, r1.y, r1.z, r1.w };
                #pragma unroll
                for (int a = 0; a < 4; ++a) {
                    if (a <= u && (u - a) <= 4) {
                        const int wu = u - a;
                        #pragma unroll
                        for (int b = 0; b < 4; ++b) {
                            float s0 = acc[a * 4 + b];
                            #pragma unroll
                            for (int v = 0; v < 5; ++v)
                                s0 = fmaf(rr[b + v], wv[wu * 5 + v], s0);
                            acc[a * 4 + b] = s0;
                        }
                    }
                }
            }
        }
        float bias = b2s[oc];
        #pragma unroll
        for (int a2 = 0; a2 < 2; ++a2)
            #pragma unroll
            for (int b2i = 0; b2i < 2; ++b2i) {
                float m = fmaxf(fmaxf(acc[(2*a2)*4 + 2*b2i], acc[(2*a2)*4 + 2*b2i + 1]),
                                fmaxf(acc[(2*a2+1)*4 + 2*b2i], acc[(2*a2+1)*4 + 2*b2i + 1]));
                hbuf[s * 256 + oc * 16 + (2*qi + a2) * 4 + (2*qj + b2i)] = fmaxf(m + bias, 0.f);
            }
    }
    __syncthreads();

    // ---- fc1 partials: thread (k=t&63, chunk=t>>6) covers 16 float4 of row k ----
    {
        int k = t & 63, chunk = t >> 6;
        const float4* wrow = (const float4*)(fw1 + k * 256) + chunk * 16;
        float part[4] = { 0.f, 0.f, 0.f, 0.f };
        #pragma unroll
        for (int n = 0; n < 16; ++n) {
            float4 w4 = wrow[n];
            #pragma unroll
            for (int s2 = 0; s2 < 4; ++s2) {
                float4 h4 = hb4[s2 * 64 + chunk * 16 + n];   // wave-uniform broadcast
                part[s2] = fmaf(w4.x, h4.x, part[s2]);
                part[s2] = fmaf(w4.y, h4.y, part[s2]);
                part[s2] = fmaf(w4.z, h4.z, part[s2]);
                part[s2] = fmaf(w4.w, h4.w, part[s2]);
            }
        }
        #pragma unroll
        for (int s2 = 0; s2 < 4; ++s2)
            pbuf[chunk * 256 + s2 * 64 + k] = part[s2];
    }
    __syncthreads();

    // ---- fc1 final + fc2 (wave reduce) + quantum + fc3 + log_softmax ----
    {
        int s = t >> 6, k = t & 63;
        float acc = fb1[k] + pbuf[s * 64 + k] + pbuf[256 + s * 64 + k]
                  + pbuf[512 + s * 64 + k] + pbuf[768 + s * 64 + k];
        float a = fmaxf(acc, 0.f);
        float pz0 = a * fw2[k];
        float pz1 = a * fw2[64 + k];
        #pragma unroll
        for (int off = 32; off > 0; off >>= 1) {
            pz0 += __shfl_xor(pz0, off, 64);
            pz1 += __shfl_xor(pz1, off, 64);
        }
        float x0 = pz0 + fb2[0];
        float x1 = pz1 + fb2[1];

        // 2-qubit circuit (all lanes redundantly)
        float sr[4], si[4];
        {
            float th0 = -x0 - x1, th1 = -x0 + x1, th2 = x0 - x1, th3 = x0 + x1;
            sr[0] = 0.5f * __cosf(th0); si[0] = 0.5f * __sinf(th0);
            sr[1] = 0.5f * __cosf(th1); si[1] = 0.5f * __sinf(th1);
            sr[2] = 0.5f * __cosf(th2); si[2] = 0.5f * __sinf(th2);
            sr[3] = 0.5f * __cosf(th3); si[3] = 0.5f * __sinf(th3);
        }
        // cnot01 (swap 2,3), phase(ang) on qubit1, cnot01 again
        {
            float tr = sr[2]; sr[2] = sr[3]; sr[3] = tr;
            float ti = si[2]; si[2] = si[3]; si[3] = ti;
            float ang = ((float)M_PI - x0) * ((float)M_PI - x1);
            float ca = __cosf(ang), sa = __sinf(ang);
            float r, im;
            r = sr[0]; im = si[0]; sr[0] = r*ca + im*sa; si[0] = im*ca - r*sa;
            r = sr[2]; im = si[2]; sr[2] = r*ca + im*sa; si[2] = im*ca - r*sa;
            r = sr[1]; im = si[1]; sr[1] = r*ca - im*sa; si[1] = im*ca + r*sa;
            r = sr[3]; im = si[3]; sr[3] = r*ca - im*sa; si[3] = im*ca + r*sa;
            tr = sr[2]; sr[2] = sr[3]; sr[3] = tr;
            ti = si[2]; si[2] = si[3]; si[3] = ti;
        }
        float cp[8], sp[8];
        #pragma unroll
        for (int g = 0; g < 8; ++g) { float q = qp[g]; cp[g] = __cosf(q); sp[g] = __sinf(q); }

        #define QRY0(cc, ss) { \
            float a0r=sr[0], a0i=si[0], a1r=sr[2], a1i=si[2]; \
            sr[0]=cc*a0r-ss*a1r; si[0]=cc*a0i-ss*a1i; \
            sr[2]=ss*a0r+cc*a1r; si[2]=ss*a0i+cc*a1i; \
            float b0r=sr[1], b0i=si[1], b1r=sr[3], b1i=si[3]; \
            sr[1]=cc*b0r-ss*b1r; si[1]=cc*b0i-ss*b1i; \
            sr[3]=ss*b0r+cc*b1r; si[3]=ss*b0i+cc*b1i; }
        #define QRY1(cc, ss) { \
            float a0r=sr[0], a0i=si[0], a1r=sr[1], a1i=si[1]; \
            sr[0]=cc*a0r-ss*a1r; si[0]=cc*a0i-ss*a1i; \
            sr[1]=ss*a0r+cc*a1r; si[1]=ss*a0i+cc*a1i; \
            float b0r=sr[2], b0i=si[2], b1r=sr[3], b1i=si[3]; \
            sr[2]=cc*b0r-ss*b1r; si[2]=cc*b0i-ss*b1i; \
            sr[3]=ss*b0r+cc*b1r; si[3]=ss*b0i+cc*b1i; }
        #define QSWAP(i_, j_) { float tr=sr[i_]; sr[i_]=sr[j_]; sr[j_]=tr; \
                                float ti=si[i_]; si[i_]=si[j_]; si[j_]=ti; }

        QRY0(cp[0], sp[0]);
        QRY1(cp[1], sp[1]);
        QSWAP(2, 3);                 // cnot01
        QRY0(cp[2], sp[2]);
        QRY1(cp[3], sp[3]);
        QSWAP(1, 3);                 // cnot10
        QRY0(cp[4], sp[4]);
        QRY1(cp[5], sp[5]);
        QSWAP(2, 3);                 // cnot01
        QRY0(cp[6], sp[6]);
        QRY1(cp[7], sp[7]);

        float qv = (sr[0]*sr[0] + si[0]*si[0])
                 - (sr[1]*sr[1] + si[1]*si[1])
                 - (sr[2]*sr[2] + si[2]*si[2])
                 + (sr[3]*sr[3] + si[3]*si[3]);
        float y = fmaf(qv, fw3[0], fb3[0]);
        float l0 = y, l1 = 1.0f - y;
        float m = fmaxf(l0, l1);
        float lse = m + __logf(__expf(l0 - m) + __expf(l1 - m));
        if (k < 2) {
            float o = (k == 0) ? (l0 - lse) : (l1 - lse);
            out[(base + s) * 2 + k] = o;
        }
        #undef QRY0
        #undef QRY1
        #undef QSWAP
    }
}

extern "C" void kernel_launch(void* const* d_in, const int* in_sizes, int n_in,
                              void* d_out, int out_size, void* d_ws, size_t ws_size,
                              hipStream_t stream) {
    const float* x   = (const float*)d_in[0];
    const float* w1  = (const float*)d_in[1];
    const float* b1  = (const float*)d_in[2];
    const float* w2  = (const float*)d_in[3];
    const float* b2  = (const float*)d_in[4];
    const float* fw1 = (const float*)d_in[5];
    const float* fb1 = (const float*)d_in[6];
    const float* fw2 = (const float*)d_in[7];
    const float* fb2 = (const float*)d_in[8];
    const float* fw3 = (const float*)d_in[9];
    const float* fb3 = (const float*)d_in[10];
    const float* qp  = (const float*)d_in[11];
    float* outp = (float*)d_out;

    int B = in_sizes[0] / 784;     // 65536
    int nblk = B / 4;              // 4 samples per block
    hipLaunchKernelGGL(hqcnn_fused, dim3(nblk), dim3(256), 0, stream,
                       x, w1, b1, w2, b2, fw1, fb1, fw2, fb2, fw3, fb3, qp, outp);
}